// Round 8
// baseline (80.345 us; speedup 1.0000x reference)
//
#include <hip/hip_runtime.h>

// PillarFeatureNet fused, 4 kernels, single feature read:
//  K1 pfn_main: wave-per-pillar-run; stages pillar to LDS; per-lane raw
//     second moments q2[10] (own points); per-pillar bias-FREE extrema
//     (channel pairs packed f32x2, broadcast LDS reads); per-pillar record
//     rec[k] = {sv[4]} {rall[3], nv} via 7 interleaved shfl chains.
//     Slim register state (<64 VGPR -> 8 waves/SIMD).
//  K1b pfn_cross: 20000 records -> Q1/S/U1/U2 cross-moment partials.
//  K2 pfn_finalize: reduce partials (A: q2 rows, B: cross rows), assemble
//     54 augmented moments (verified R7 index maps), scale/shift.
//  K3 pfn_apply: per-pillar bias from rec, extremum select by sign(scale),
//     BN affine + relu.
// features [K,P,4] f32, num_voxels [K] i32, coors [K,4] i32,
// W [9,64] f32, gamma/beta [64] f32 -> out [K,64] f32.

typedef float f32x2 __attribute__((ext_vector_type(2)));

#define NBA 1252  // K1 blocks (divisible by 4 for K2 chunking)
#define NBB 64    // K1b blocks

__device__ __forceinline__ float wred_add(float v) {
#pragma unroll
  for (int off = 1; off < 64; off <<= 1) v += __shfl_xor(v, off, 64);
  return v;
}
__device__ __forceinline__ f32x2 pmax2(f32x2 a, f32x2 b) {
  f32x2 r; r.x = fmaxf(a.x, b.x); r.y = fmaxf(a.y, b.y); return r;
}
__device__ __forceinline__ f32x2 pmin2(f32x2 a, f32x2 b) {
  f32x2 r; r.x = fminf(a.x, b.x); r.y = fminf(a.y, b.y); return r;
}

// ---------------- K1 ----------------
__global__ void __launch_bounds__(512, 8) pfn_main(
    const float4* __restrict__ feat, const int* __restrict__ nvox, int K,
    int P, int cnt, const float* __restrict__ W, float* __restrict__ pA,
    float4* __restrict__ ext, float4* __restrict__ rec) {
  __shared__ float4 pts[8][104];
  __shared__ float red[8][10];
  const int lane = threadIdx.x & 63;
  const int wid = threadIdx.x >> 6;
  const int hl = lane & 31;
  const int p0 = lane >> 5;  // half id: even/odd point stream

  // folded weights for this lane's channel pair (bias handled in K3)
  const f32x2* W2 = (const f32x2*)W;  // [9][32]
  const f32x2 wx = W2[0 * 32 + hl] + W2[4 * 32 + hl] + W2[7 * 32 + hl];
  const f32x2 wy = W2[1 * 32 + hl] + W2[5 * 32 + hl] + W2[8 * 32 + hl];
  const f32x2 wz = W2[2 * 32 + hl] + W2[6 * 32 + hl];
  const f32x2 w3 = W2[3 * 32 + hl];

  float q2[10] = {0, 0, 0, 0, 0, 0, 0, 0, 0, 0};

  const int gw = blockIdx.x * 8 + wid;
  const int k0 = gw * cnt;
  const int kend = (k0 + cnt < K) ? k0 + cnt : K;

  if (k0 < kend) {
    const bool hih = (64 + lane) < P;
    float4 f0 = feat[(size_t)k0 * P + lane];
    float4 f1;
    if (hih) f1 = feat[(size_t)k0 * P + 64 + lane];
    int nv = nvox[k0];
    for (int k = k0; k < kend; ++k) {
      // ---- stage (single buffer; same-wave LDS ordering makes it safe) ----
      pts[wid][lane] = f0;
      if (hih) pts[wid][64 + lane] = f1;
      if ((nv & 1) && lane == 0) pts[wid][nv] = f0;  // dup valid pt -> odd slot

      // ---- per-lane sums + raw second moments from registers ----
      float sax = f0.x, say = f0.y, saz = f0.z;
      float svx = 0, svy = 0, svz = 0, svw = 0;
      if (lane < nv) {
        svx = f0.x; svy = f0.y; svz = f0.z; svw = f0.w;
        q2[0] = fmaf(f0.x, f0.x, q2[0]); q2[1] = fmaf(f0.x, f0.y, q2[1]);
        q2[2] = fmaf(f0.x, f0.z, q2[2]); q2[3] = fmaf(f0.x, f0.w, q2[3]);
        q2[4] = fmaf(f0.y, f0.y, q2[4]); q2[5] = fmaf(f0.y, f0.z, q2[5]);
        q2[6] = fmaf(f0.y, f0.w, q2[6]); q2[7] = fmaf(f0.z, f0.z, q2[7]);
        q2[8] = fmaf(f0.z, f0.w, q2[8]); q2[9] = fmaf(f0.w, f0.w, q2[9]);
      }
      if (hih) {
        sax += f1.x; say += f1.y; saz += f1.z;
        if (64 + lane < nv) {
          svx += f1.x; svy += f1.y; svz += f1.z; svw += f1.w;
          q2[0] = fmaf(f1.x, f1.x, q2[0]); q2[1] = fmaf(f1.x, f1.y, q2[1]);
          q2[2] = fmaf(f1.x, f1.z, q2[2]); q2[3] = fmaf(f1.x, f1.w, q2[3]);
          q2[4] = fmaf(f1.y, f1.y, q2[4]); q2[5] = fmaf(f1.y, f1.z, q2[5]);
          q2[6] = fmaf(f1.y, f1.w, q2[6]); q2[7] = fmaf(f1.z, f1.z, q2[7]);
          q2[8] = fmaf(f1.z, f1.w, q2[8]); q2[9] = fmaf(f1.w, f1.w, q2[9]);
        }
      }

      // ---- prefetch next pillar (hides under extrema loop) ----
      float4 f0n, f1n;
      int nvn = nv;
      if (k + 1 < kend) {
        f0n = feat[(size_t)(k + 1) * P + lane];
        if (hih) f1n = feat[(size_t)(k + 1) * P + 64 + lane];
        nvn = nvox[k + 1];
      }

      // ---- bias-free extrema over staged valid points ----
      const int nvv = nv + (nv & 1);
      f32x2 bm0 = {-3e38f, -3e38f}, bm1 = {-3e38f, -3e38f};
      f32x2 bn0 = {3e38f, 3e38f}, bn1 = {3e38f, 3e38f};
      int p = 0;
      for (; p + 4 <= nvv; p += 4) {
        float4 fa = pts[wid][p + p0];
        float4 fb = pts[wid][p + 2 + p0];
        f32x2 ba = wx * fa.x + wy * fa.y + wz * fa.z + w3 * fa.w;
        f32x2 bb = wx * fb.x + wy * fb.y + wz * fb.z + w3 * fb.w;
        bm0 = pmax2(bm0, ba); bn0 = pmin2(bn0, ba);
        bm1 = pmax2(bm1, bb); bn1 = pmin2(bn1, bb);
      }
      if (p < nvv) {
        float4 fa = pts[wid][p + p0];
        f32x2 ba = wx * fa.x + wy * fa.y + wz * fa.z + w3 * fa.w;
        bm0 = pmax2(bm0, ba); bn0 = pmin2(bn0, ba);
      }
      f32x2 bm = pmax2(bm0, bm1), bn = pmin2(bn0, bn1);
      f32x2 tsw;
      tsw.x = __shfl_xor(bm.x, 32, 64); tsw.y = __shfl_xor(bm.y, 32, 64);
      bm = pmax2(bm, tsw);
      tsw.x = __shfl_xor(bn.x, 32, 64); tsw.y = __shfl_xor(bn.y, 32, 64);
      bn = pmin2(bn, tsw);
      if (lane < 32) {
        float4 e; e.x = bm.x; e.y = bm.y; e.z = bn.x; e.w = bn.y;
        ext[(size_t)k * 32 + hl] = e;
      }

      // ---- 7 interleaved shfl chains -> per-pillar record ----
      float rx = sax, ry = say, rz = saz;
#pragma unroll
      for (int off = 1; off < 64; off <<= 1) {
        rx += __shfl_xor(rx, off, 64);
        ry += __shfl_xor(ry, off, 64);
        rz += __shfl_xor(rz, off, 64);
        svx += __shfl_xor(svx, off, 64);
        svy += __shfl_xor(svy, off, 64);
        svz += __shfl_xor(svz, off, 64);
        svw += __shfl_xor(svw, off, 64);
      }
      if (lane == 0) {
        float4 r0; r0.x = svx; r0.y = svy; r0.z = svz; r0.w = svw;
        float4 r1; r1.x = rx; r1.y = ry; r1.z = rz; r1.w = (float)nv;
        rec[2 * (size_t)k] = r0;
        rec[2 * (size_t)k + 1] = r1;
      }

      f0 = f0n; f1 = f1n; nv = nvn;
    }
  }

  // ---- block-level q2 partials (deterministic) ----
#pragma unroll
  for (int i = 0; i < 10; ++i) q2[i] = wred_add(q2[i]);
  if (lane == 0) {
#pragma unroll
    for (int i = 0; i < 10; ++i) red[wid][i] = q2[i];
  }
  __syncthreads();
  const int t = threadIdx.x;
  if (t < 10) {
    float s = 0.f;
#pragma unroll
    for (int w = 0; w < 8; ++w) s += red[w][t];
    pA[t * NBA + blockIdx.x] = s;
  }
}

// ---------------- K1b: cross-moment aggregation from records ----------------
__global__ void __launch_bounds__(256) pfn_cross(
    const float4* __restrict__ rec, const int* __restrict__ coors, int K,
    float* __restrict__ pB) {
  __shared__ float red[4][44];
  const int lane = threadIdx.x & 63;
  const int wid = threadIdx.x >> 6;
  float q1[4] = {0, 0, 0, 0};
  float S[20];
  float u1[5] = {0, 0, 0, 0, 0};
  float u2[15];
#pragma unroll
  for (int i = 0; i < 20; ++i) S[i] = 0.f;
#pragma unroll
  for (int i = 0; i < 15; ++i) u2[i] = 0.f;

  for (int k = blockIdx.x * 256 + threadIdx.x; k < K; k += NBB * 256) {
    const float4 sv = rec[2 * (size_t)k];
    const float4 rb = rec[2 * (size_t)k + 1];
    const float nvf = rb.w, inv = 1.f / nvf;
    const float cx = (float)coors[k * 4 + 3] * 0.2f + 0.1f;
    const float cy = (float)coors[k * 4 + 2] * 0.2f - 39.9f;
    const float o[5] = {-rb.x * inv, -rb.y * inv, -rb.z * inv, -cx, -cy};
    const float s4[4] = {sv.x, sv.y, sv.z, sv.w};
#pragma unroll
    for (int a = 0; a < 4; ++a) q1[a] += s4[a];
#pragma unroll
    for (int a = 0; a < 4; ++a)
#pragma unroll
      for (int b = 0; b < 5; ++b)
        S[a * 5 + b] = fmaf(s4[a], o[b], S[a * 5 + b]);
    float no[5];
#pragma unroll
    for (int b = 0; b < 5; ++b) { no[b] = nvf * o[b]; u1[b] += no[b]; }
    int ui = 0;
#pragma unroll
    for (int b = 0; b < 5; ++b)
#pragma unroll
      for (int b2 = b; b2 < 5; ++b2) {
        u2[ui] = fmaf(no[b], o[b2], u2[ui]);
        ++ui;
      }
  }

  float a44[44];
#pragma unroll
  for (int i = 0; i < 4; ++i) a44[i] = q1[i];
#pragma unroll
  for (int i = 0; i < 20; ++i) a44[4 + i] = S[i];
#pragma unroll
  for (int i = 0; i < 5; ++i) a44[24 + i] = u1[i];
#pragma unroll
  for (int i = 0; i < 15; ++i) a44[29 + i] = u2[i];
#pragma unroll
  for (int i = 0; i < 44; ++i) a44[i] = wred_add(a44[i]);
  if (lane == 0) {
#pragma unroll
    for (int i = 0; i < 44; ++i) red[wid][i] = a44[i];
  }
  __syncthreads();
  const int t = threadIdx.x;
  if (t < 44)
    pB[t * NBB + blockIdx.x] =
        red[0][t] + red[1][t] + red[2][t] + red[3][t];
}

// ---------------- K2: reduce + assemble + scale/shift ----------------
__global__ void __launch_bounds__(256) pfn_finalize(
    const float* __restrict__ pA, const float* __restrict__ pB,
    const float* __restrict__ W, const float* __restrict__ gamma,
    const float* __restrict__ beta, float invN, float* __restrict__ ss) {
  __shared__ float msum[54];
  __shared__ float m54[54];
  const int t = threadIdx.x;
  const int r = t >> 2, j = t & 3;
  if (r < 54) {
    const float* row;
    int nb;
    if (r >= 4 && r < 14) { row = pA + (size_t)(r - 4) * NBA; nb = NBA; }
    else {
      const int br = (r < 4) ? r : (r - 10);
      row = pB + (size_t)br * NBB;
      nb = NBB;
    }
    const int chunk = nb >> 2;
    row += j * chunk;
    float a0 = 0, a1 = 0, a2 = 0, a3 = 0, a4 = 0, a5 = 0, a6 = 0, a7 = 0;
    int b = 0;
    for (; b + 8 <= chunk; b += 8) {
      a0 += row[b];     a1 += row[b + 1]; a2 += row[b + 2]; a3 += row[b + 3];
      a4 += row[b + 4]; a5 += row[b + 5]; a6 += row[b + 6]; a7 += row[b + 7];
    }
    for (; b < chunk; ++b) a0 += row[b];
    float s = ((a0 + a1) + (a2 + a3)) + ((a4 + a5) + (a6 + a7));
    s += __shfl_xor(s, 1, 64);
    s += __shfl_xor(s, 2, 64);
    if (j == 0) msum[r] = s;
  }
  __syncthreads();
  // msum layout: [0..3]=Q1 [4..13]=Q2 [14..33]=S [34..38]=U1 [39..53]=U2
  if (t < 54) {
    float v;
    if (t < 9) {
      const int g = (t < 4) ? t : (t < 7 ? t - 4 : t - 7);
      v = msum[g];
      if (t >= 4) v += msum[34 + (t - 4)];
    } else {
      int r2 = t - 9, c = 0;
      while (r2 >= 9 - c) { r2 -= 9 - c; ++c; }
      const int c2 = c + r2;
      const int a = (c < 4) ? c : (c < 7 ? c - 4 : c - 7);
      const int b2 = (c2 < 4) ? c2 : (c2 < 7 ? c2 - 4 : c2 - 7);
      const int lo = a < b2 ? a : b2, hi = a < b2 ? b2 : a;
      v = msum[4 + lo * (9 - lo) / 2 + (hi - lo)];  // 4x4 tri offsets 0/4/7/9
      if (c2 >= 4) v += msum[14 + a * 5 + (c2 - 4)];
      if (c >= 4) v += msum[14 + b2 * 5 + (c - 4)];
      if (c >= 4 && c2 >= 4) {
        const int ua = c - 4, ub = c2 - 4;  // ua <= ub
        v += msum[39 + ua * 5 - ua * (ua - 1) / 2 + (ub - ua)];
      }
    }
    m54[t] = v;
  }
  __syncthreads();
  if (t < 64) {
    float wc[9];
#pragma unroll
    for (int c = 0; c < 9; ++c) wc[c] = W[c * 64 + t];
    float mu = 0.f;
#pragma unroll
    for (int c = 0; c < 9; ++c) mu += m54[c] * invN * wc[c];
    float ex2 = 0.f;
    int idx = 9;
#pragma unroll
    for (int c = 0; c < 9; ++c)
#pragma unroll
      for (int c2 = c; c2 < 9; ++c2) {
        float v = m54[idx] * invN * wc[c] * wc[c2];
        ex2 += (c == c2) ? v : 2.f * v;
        ++idx;
      }
    const float var = ex2 - mu * mu;
    const float scale = gamma[t] * rsqrtf(var + 1e-3f);
    ss[t] = scale;
    ss[64 + t] = beta[t] - mu * scale;
  }
}

// ---------------- K3: bias + select + BN + relu ----------------
__global__ void __launch_bounds__(512) pfn_apply(
    const float4* __restrict__ ext, const float4* __restrict__ rec,
    const int* __restrict__ coors, const float* __restrict__ W,
    const float* __restrict__ ss, int K, int P, f32x2* __restrict__ out) {
  const int lane = threadIdx.x & 63;
  const int wid = threadIdx.x >> 6;
  const int hl = lane & 31;
  const int k = (blockIdx.x * 8 + wid) * 2 + (lane >> 5);
  if (k >= K) return;

  const f32x2* W2 = (const f32x2*)W;
  const f32x2 v4 = W2[4 * 32 + hl], v5 = W2[5 * 32 + hl];
  const f32x2 v6 = W2[6 * 32 + hl], v7 = W2[7 * 32 + hl];
  const f32x2 v8 = W2[8 * 32 + hl];

  const float4 e = ext[(size_t)k * 32 + hl];
  const float4 rb = rec[2 * (size_t)k + 1];
  const float nvf = rb.w, inv = 1.f / nvf;
  const float cx = (float)coors[k * 4 + 3] * 0.2f + 0.1f;
  const float cy = (float)coors[k * 4 + 2] * 0.2f - 39.9f;
  const float o0 = -rb.x * inv, o1 = -rb.y * inv, o2 = -rb.z * inv;
  const f32x2 bias = v4 * o0 + v5 * o1 + v6 * o2 + v7 * (-cx) + v8 * (-cy);

  f32x2 vmax, vmin;
  vmax.x = e.x + bias.x; vmax.y = e.y + bias.y;
  vmin.x = e.z + bias.x; vmin.y = e.w + bias.y;
  if (nvf < (float)P) {  // masked rows contribute raw x == 0
    vmax.x = fmaxf(vmax.x, 0.f); vmax.y = fmaxf(vmax.y, 0.f);
    vmin.x = fminf(vmin.x, 0.f); vmin.y = fminf(vmin.y, 0.f);
  }
  const f32x2 sc = ((const f32x2*)ss)[hl];
  const f32x2 sh = ((const f32x2*)(ss + 64))[hl];
  const float s0 = (sc.x >= 0.f) ? vmax.x : vmin.x;
  const float s1 = (sc.y >= 0.f) ? vmax.y : vmin.y;
  f32x2 o;
  o.x = fmaxf(fmaf(sc.x, s0, sh.x), 0.f);
  o.y = fmaxf(fmaf(sc.y, s1, sh.y), 0.f);
  out[(size_t)k * 32 + hl] = o;
}

extern "C" void kernel_launch(void* const* d_in, const int* in_sizes, int n_in,
                              void* d_out, int out_size, void* d_ws,
                              size_t ws_size, hipStream_t stream) {
  const float4* feat = (const float4*)d_in[0];
  const int* nvox = (const int*)d_in[1];
  const int* coors = (const int*)d_in[2];
  const float* W = (const float*)d_in[3];
  const float* gamma = (const float*)d_in[4];
  const float* beta = (const float*)d_in[5];
  float* out = (float*)d_out;

  const int K = in_sizes[1];
  const int P = in_sizes[0] / (K * 4);

  // ws layout (floats): ss[128] | ext[K*32 float4] | rec[K*2 float4]
  //                     | pA[10*NBA] | pB[44*NBB]   (~11 MB total)
  float* ss = (float*)d_ws;
  float4* ext = (float4*)(ss + 128);
  float4* rec = ext + (size_t)K * 32;
  float* pA = (float*)(rec + (size_t)K * 2);
  float* pB = pA + 10 * NBA;

  const int nwaves = NBA * 8;
  const int cnt = (K + nwaves - 1) / nwaves;

  pfn_main<<<NBA, 512, 0, stream>>>(feat, nvox, K, P, cnt, W, pA, ext, rec);
  pfn_cross<<<NBB, 256, 0, stream>>>(rec, coors, K, pB);
  pfn_finalize<<<1, 256, 0, stream>>>(pA, pB, W, gamma, beta,
                                      1.0f / (float)((long long)K * P), ss);
  pfn_apply<<<(K + 15) / 16, 512, 0, stream>>>(ext, rec, coors, W, ss, K, P,
                                               (f32x2*)out);
}

// Round 9
// 52.292 us; speedup vs baseline: 1.5365x; 1.5365x over previous
//
#include <hip/hip_runtime.h>

// PillarFeatureNet fused, 4 kernels, single feature read:
//  K1 pfn_main: wave-per-pillar-run; stages pillar to LDS; per-lane raw
//     second moments q2[10]; bias-free extrema (channel pairs f32x2,
//     broadcast LDS reads, even/odd half split); per-pillar record
//     rec[k] = {sv[4]} {rall[3], nv} via DPP+shfl hybrid reductions.
//     Slim register state (no prefetch, no forced occupancy).
//  K1b pfn_cross: records -> Q1/S/U1/U2 cross-moment partials.
//  K2 pfn_finalize: reduce partials, assemble 54 augmented moments
//     (verified index maps), per-channel scale/shift.
//  K3 pfn_apply: per-pillar bias from rec, extremum select by sign(scale),
//     BN affine + relu.
// features [K,P,4] f32, num_voxels [K] i32, coors [K,4] i32,
// W [9,64] f32, gamma/beta [64] f32 -> out [K,64] f32.

typedef float f32x2 __attribute__((ext_vector_type(2)));

#define NBA 1252  // K1 blocks (divisible by 4 for K2 chunking)
#define NBB 64    // K1b blocks

// Butterfly sum: 4 DPP steps (xor1, xor2, xor7, xor15 -> row-of-16 sum in
// all lanes), then 2 shfl_xor for the 16/32 crossings. All-lane result.
__device__ __forceinline__ float wred_add(float v) {
  int t;
  t = __builtin_amdgcn_update_dpp(0, __float_as_int(v), 0xB1, 0xf, 0xf, true);
  v += __int_as_float(t);  // quad_perm(1,0,3,2) = xor1
  t = __builtin_amdgcn_update_dpp(0, __float_as_int(v), 0x4E, 0xf, 0xf, true);
  v += __int_as_float(t);  // quad_perm(2,3,0,1) = xor2
  t = __builtin_amdgcn_update_dpp(0, __float_as_int(v), 0x141, 0xf, 0xf, true);
  v += __int_as_float(t);  // row_half_mirror = xor7
  t = __builtin_amdgcn_update_dpp(0, __float_as_int(v), 0x140, 0xf, 0xf, true);
  v += __int_as_float(t);  // row_mirror = xor15
  v += __shfl_xor(v, 16, 64);
  v += __shfl_xor(v, 32, 64);
  return v;
}
__device__ __forceinline__ f32x2 pmax2(f32x2 a, f32x2 b) {
  f32x2 r; r.x = fmaxf(a.x, b.x); r.y = fmaxf(a.y, b.y); return r;
}
__device__ __forceinline__ f32x2 pmin2(f32x2 a, f32x2 b) {
  f32x2 r; r.x = fminf(a.x, b.x); r.y = fminf(a.y, b.y); return r;
}

// ---------------- K1 ----------------
__global__ void __launch_bounds__(512) pfn_main(
    const float4* __restrict__ feat, const int* __restrict__ nvox, int K,
    int P, int cnt, const float* __restrict__ W, float* __restrict__ pA,
    float4* __restrict__ ext, float4* __restrict__ rec) {
  __shared__ float4 pts[8][104];
  __shared__ float red[8][10];
  const int lane = threadIdx.x & 63;
  const int wid = threadIdx.x >> 6;
  const int hl = lane & 31;
  const int p0 = lane >> 5;  // half id: even/odd point stream

  // folded weights for this lane's channel pair (bias handled in K3)
  const f32x2* W2 = (const f32x2*)W;  // [9][32]
  const f32x2 wx = W2[0 * 32 + hl] + W2[4 * 32 + hl] + W2[7 * 32 + hl];
  const f32x2 wy = W2[1 * 32 + hl] + W2[5 * 32 + hl] + W2[8 * 32 + hl];
  const f32x2 wz = W2[2 * 32 + hl] + W2[6 * 32 + hl];
  const f32x2 w3 = W2[3 * 32 + hl];

  float q2[10] = {0, 0, 0, 0, 0, 0, 0, 0, 0, 0};

  const int gw = blockIdx.x * 8 + wid;
  const int k0 = gw * cnt;
  const int kend = (k0 + cnt < K) ? k0 + cnt : K;
  const bool hih = (64 + lane) < P;

  for (int k = k0; k < kend; ++k) {
    const size_t base = (size_t)k * P;
    const float4 f0 = feat[base + lane];
    float4 f1;
    if (hih) f1 = feat[base + 64 + lane];
    const int nv = nvox[k];

    // ---- stage (single buffer; same-wave LDS ordering is safe) ----
    pts[wid][lane] = f0;
    if (hih) pts[wid][64 + lane] = f1;
    if ((nv & 1) && lane == 0) pts[wid][nv] = f0;  // dup valid pt -> odd slot

    // ---- per-lane sums + raw second moments from registers ----
    float sax = f0.x, say = f0.y, saz = f0.z;
    float svx = 0, svy = 0, svz = 0, svw = 0;
    if (lane < nv) {
      svx = f0.x; svy = f0.y; svz = f0.z; svw = f0.w;
      q2[0] = fmaf(f0.x, f0.x, q2[0]); q2[1] = fmaf(f0.x, f0.y, q2[1]);
      q2[2] = fmaf(f0.x, f0.z, q2[2]); q2[3] = fmaf(f0.x, f0.w, q2[3]);
      q2[4] = fmaf(f0.y, f0.y, q2[4]); q2[5] = fmaf(f0.y, f0.z, q2[5]);
      q2[6] = fmaf(f0.y, f0.w, q2[6]); q2[7] = fmaf(f0.z, f0.z, q2[7]);
      q2[8] = fmaf(f0.z, f0.w, q2[8]); q2[9] = fmaf(f0.w, f0.w, q2[9]);
    }
    if (hih) {
      sax += f1.x; say += f1.y; saz += f1.z;
      if (64 + lane < nv) {
        svx += f1.x; svy += f1.y; svz += f1.z; svw += f1.w;
        q2[0] = fmaf(f1.x, f1.x, q2[0]); q2[1] = fmaf(f1.x, f1.y, q2[1]);
        q2[2] = fmaf(f1.x, f1.z, q2[2]); q2[3] = fmaf(f1.x, f1.w, q2[3]);
        q2[4] = fmaf(f1.y, f1.y, q2[4]); q2[5] = fmaf(f1.y, f1.z, q2[5]);
        q2[6] = fmaf(f1.y, f1.w, q2[6]); q2[7] = fmaf(f1.z, f1.z, q2[7]);
        q2[8] = fmaf(f1.z, f1.w, q2[8]); q2[9] = fmaf(f1.w, f1.w, q2[9]);
      }
    }

    // ---- 7 reductions (DPP+shfl hybrid, mostly VALU) ----
    const float rx = wred_add(sax);
    const float ry = wred_add(say);
    const float rz = wred_add(saz);
    svx = wred_add(svx);
    svy = wred_add(svy);
    svz = wred_add(svz);
    svw = wred_add(svw);

    // ---- bias-free extrema over staged valid points ----
    const int nvv = nv + (nv & 1);
    f32x2 bm0 = {-3e38f, -3e38f}, bm1 = {-3e38f, -3e38f};
    f32x2 bn0 = {3e38f, 3e38f}, bn1 = {3e38f, 3e38f};
    int p = 0;
    for (; p + 4 <= nvv; p += 4) {
      float4 fa = pts[wid][p + p0];
      float4 fb = pts[wid][p + 2 + p0];
      f32x2 ba = wx * fa.x + wy * fa.y + wz * fa.z + w3 * fa.w;
      f32x2 bb = wx * fb.x + wy * fb.y + wz * fb.z + w3 * fb.w;
      bm0 = pmax2(bm0, ba); bn0 = pmin2(bn0, ba);
      bm1 = pmax2(bm1, bb); bn1 = pmin2(bn1, bb);
    }
    if (p < nvv) {
      float4 fa = pts[wid][p + p0];
      f32x2 ba = wx * fa.x + wy * fa.y + wz * fa.z + w3 * fa.w;
      bm0 = pmax2(bm0, ba); bn0 = pmin2(bn0, ba);
    }
    f32x2 bm = pmax2(bm0, bm1), bn = pmin2(bn0, bn1);
    f32x2 tsw;
    tsw.x = __shfl_xor(bm.x, 32, 64); tsw.y = __shfl_xor(bm.y, 32, 64);
    bm = pmax2(bm, tsw);
    tsw.x = __shfl_xor(bn.x, 32, 64); tsw.y = __shfl_xor(bn.y, 32, 64);
    bn = pmin2(bn, tsw);
    if (lane < 32) {
      float4 e; e.x = bm.x; e.y = bm.y; e.z = bn.x; e.w = bn.y;
      ext[(size_t)k * 32 + hl] = e;
    }
    if (lane == 0) {
      float4 r0; r0.x = svx; r0.y = svy; r0.z = svz; r0.w = svw;
      float4 r1; r1.x = rx; r1.y = ry; r1.z = rz; r1.w = (float)nv;
      rec[2 * (size_t)k] = r0;
      rec[2 * (size_t)k + 1] = r1;
    }
  }

  // ---- block-level q2 partials (deterministic) ----
#pragma unroll
  for (int i = 0; i < 10; ++i) q2[i] = wred_add(q2[i]);
  if (lane == 0) {
#pragma unroll
    for (int i = 0; i < 10; ++i) red[wid][i] = q2[i];
  }
  __syncthreads();
  const int t = threadIdx.x;
  if (t < 10) {
    float s = 0.f;
#pragma unroll
    for (int w = 0; w < 8; ++w) s += red[w][t];
    pA[t * NBA + blockIdx.x] = s;
  }
}

// ---------------- K1b: cross-moment aggregation from records ----------------
__global__ void __launch_bounds__(256) pfn_cross(
    const float4* __restrict__ rec, const int* __restrict__ coors, int K,
    float* __restrict__ pB) {
  __shared__ float red[4][44];
  const int lane = threadIdx.x & 63;
  const int wid = threadIdx.x >> 6;
  float q1[4] = {0, 0, 0, 0};
  float S[20];
  float u1[5] = {0, 0, 0, 0, 0};
  float u2[15];
#pragma unroll
  for (int i = 0; i < 20; ++i) S[i] = 0.f;
#pragma unroll
  for (int i = 0; i < 15; ++i) u2[i] = 0.f;

  for (int k = blockIdx.x * 256 + threadIdx.x; k < K; k += NBB * 256) {
    const float4 sv = rec[2 * (size_t)k];
    const float4 rb = rec[2 * (size_t)k + 1];
    const float nvf = rb.w, inv = 1.f / nvf;
    const float cx = (float)coors[k * 4 + 3] * 0.2f + 0.1f;
    const float cy = (float)coors[k * 4 + 2] * 0.2f - 39.9f;
    const float o[5] = {-rb.x * inv, -rb.y * inv, -rb.z * inv, -cx, -cy};
    const float s4[4] = {sv.x, sv.y, sv.z, sv.w};
#pragma unroll
    for (int a = 0; a < 4; ++a) q1[a] += s4[a];
#pragma unroll
    for (int a = 0; a < 4; ++a)
#pragma unroll
      for (int b = 0; b < 5; ++b)
        S[a * 5 + b] = fmaf(s4[a], o[b], S[a * 5 + b]);
    float no[5];
#pragma unroll
    for (int b = 0; b < 5; ++b) { no[b] = nvf * o[b]; u1[b] += no[b]; }
    int ui = 0;
#pragma unroll
    for (int b = 0; b < 5; ++b)
#pragma unroll
      for (int b2 = b; b2 < 5; ++b2) {
        u2[ui] = fmaf(no[b], o[b2], u2[ui]);
        ++ui;
      }
  }

  float a44[44];
#pragma unroll
  for (int i = 0; i < 4; ++i) a44[i] = q1[i];
#pragma unroll
  for (int i = 0; i < 20; ++i) a44[4 + i] = S[i];
#pragma unroll
  for (int i = 0; i < 5; ++i) a44[24 + i] = u1[i];
#pragma unroll
  for (int i = 0; i < 15; ++i) a44[29 + i] = u2[i];
#pragma unroll
  for (int i = 0; i < 44; ++i) a44[i] = wred_add(a44[i]);
  if (lane == 0) {
#pragma unroll
    for (int i = 0; i < 44; ++i) red[wid][i] = a44[i];
  }
  __syncthreads();
  const int t = threadIdx.x;
  if (t < 44)
    pB[t * NBB + blockIdx.x] =
        red[0][t] + red[1][t] + red[2][t] + red[3][t];
}

// ---------------- K2: reduce + assemble + scale/shift ----------------
__global__ void __launch_bounds__(256) pfn_finalize(
    const float* __restrict__ pA, const float* __restrict__ pB,
    const float* __restrict__ W, const float* __restrict__ gamma,
    const float* __restrict__ beta, float invN, float* __restrict__ ss) {
  __shared__ float msum[54];
  __shared__ float m54[54];
  const int t = threadIdx.x;
  const int r = t >> 2, j = t & 3;
  if (r < 54) {
    const float* row;
    int nb;
    if (r >= 4 && r < 14) { row = pA + (size_t)(r - 4) * NBA; nb = NBA; }
    else {
      const int br = (r < 4) ? r : (r - 10);
      row = pB + (size_t)br * NBB;
      nb = NBB;
    }
    const int chunk = nb >> 2;
    row += j * chunk;
    float a0 = 0, a1 = 0, a2 = 0, a3 = 0, a4 = 0, a5 = 0, a6 = 0, a7 = 0;
    int b = 0;
    for (; b + 8 <= chunk; b += 8) {
      a0 += row[b];     a1 += row[b + 1]; a2 += row[b + 2]; a3 += row[b + 3];
      a4 += row[b + 4]; a5 += row[b + 5]; a6 += row[b + 6]; a7 += row[b + 7];
    }
    for (; b < chunk; ++b) a0 += row[b];
    float s = ((a0 + a1) + (a2 + a3)) + ((a4 + a5) + (a6 + a7));
    s += __shfl_xor(s, 1, 64);
    s += __shfl_xor(s, 2, 64);
    if (j == 0) msum[r] = s;
  }
  __syncthreads();
  // msum layout: [0..3]=Q1 [4..13]=Q2 [14..33]=S [34..38]=U1 [39..53]=U2
  if (t < 54) {
    float v;
    if (t < 9) {
      const int g = (t < 4) ? t : (t < 7 ? t - 4 : t - 7);
      v = msum[g];
      if (t >= 4) v += msum[34 + (t - 4)];
    } else {
      int r2 = t - 9, c = 0;
      while (r2 >= 9 - c) { r2 -= 9 - c; ++c; }
      const int c2 = c + r2;
      const int a = (c < 4) ? c : (c < 7 ? c - 4 : c - 7);
      const int b2 = (c2 < 4) ? c2 : (c2 < 7 ? c2 - 4 : c2 - 7);
      const int lo = a < b2 ? a : b2, hi = a < b2 ? b2 : a;
      v = msum[4 + lo * (9 - lo) / 2 + (hi - lo)];  // 4x4 tri offsets 0/4/7/9
      if (c2 >= 4) v += msum[14 + a * 5 + (c2 - 4)];
      if (c >= 4) v += msum[14 + b2 * 5 + (c - 4)];
      if (c >= 4 && c2 >= 4) {
        const int ua = c - 4, ub = c2 - 4;  // ua <= ub
        v += msum[39 + ua * 5 - ua * (ua - 1) / 2 + (ub - ua)];
      }
    }
    m54[t] = v;
  }
  __syncthreads();
  if (t < 64) {
    float wc[9];
#pragma unroll
    for (int c = 0; c < 9; ++c) wc[c] = W[c * 64 + t];
    float mu = 0.f;
#pragma unroll
    for (int c = 0; c < 9; ++c) mu += m54[c] * invN * wc[c];
    float ex2 = 0.f;
    int idx = 9;
#pragma unroll
    for (int c = 0; c < 9; ++c)
#pragma unroll
      for (int c2 = c; c2 < 9; ++c2) {
        float v = m54[idx] * invN * wc[c] * wc[c2];
        ex2 += (c == c2) ? v : 2.f * v;
        ++idx;
      }
    const float var = ex2 - mu * mu;
    const float scale = gamma[t] * rsqrtf(var + 1e-3f);
    ss[t] = scale;
    ss[64 + t] = beta[t] - mu * scale;
  }
}

// ---------------- K3: bias + select + BN + relu ----------------
__global__ void __launch_bounds__(512) pfn_apply(
    const float4* __restrict__ ext, const float4* __restrict__ rec,
    const int* __restrict__ coors, const float* __restrict__ W,
    const float* __restrict__ ss, int K, int P, f32x2* __restrict__ out) {
  const int lane = threadIdx.x & 63;
  const int wid = threadIdx.x >> 6;
  const int hl = lane & 31;
  const int k = (blockIdx.x * 8 + wid) * 2 + (lane >> 5);
  if (k >= K) return;

  const f32x2* W2 = (const f32x2*)W;
  const f32x2 v4 = W2[4 * 32 + hl], v5 = W2[5 * 32 + hl];
  const f32x2 v6 = W2[6 * 32 + hl], v7 = W2[7 * 32 + hl];
  const f32x2 v8 = W2[8 * 32 + hl];

  const float4 e = ext[(size_t)k * 32 + hl];
  const float4 rb = rec[2 * (size_t)k + 1];
  const float nvf = rb.w, inv = 1.f / nvf;
  const float cx = (float)coors[k * 4 + 3] * 0.2f + 0.1f;
  const float cy = (float)coors[k * 4 + 2] * 0.2f - 39.9f;
  const float o0 = -rb.x * inv, o1 = -rb.y * inv, o2 = -rb.z * inv;
  const f32x2 bias = v4 * o0 + v5 * o1 + v6 * o2 + v7 * (-cx) + v8 * (-cy);

  f32x2 vmax, vmin;
  vmax.x = e.x + bias.x; vmax.y = e.y + bias.y;
  vmin.x = e.z + bias.x; vmin.y = e.w + bias.y;
  if (nvf < (float)P) {  // masked rows contribute raw x == 0
    vmax.x = fmaxf(vmax.x, 0.f); vmax.y = fmaxf(vmax.y, 0.f);
    vmin.x = fminf(vmin.x, 0.f); vmin.y = fminf(vmin.y, 0.f);
  }
  const f32x2 sc = ((const f32x2*)ss)[hl];
  const f32x2 sh = ((const f32x2*)(ss + 64))[hl];
  const float s0 = (sc.x >= 0.f) ? vmax.x : vmin.x;
  const float s1 = (sc.y >= 0.f) ? vmax.y : vmin.y;
  f32x2 o;
  o.x = fmaxf(fmaf(sc.x, s0, sh.x), 0.f);
  o.y = fmaxf(fmaf(sc.y, s1, sh.y), 0.f);
  out[(size_t)k * 32 + hl] = o;
}

extern "C" void kernel_launch(void* const* d_in, const int* in_sizes, int n_in,
                              void* d_out, int out_size, void* d_ws,
                              size_t ws_size, hipStream_t stream) {
  const float4* feat = (const float4*)d_in[0];
  const int* nvox = (const int*)d_in[1];
  const int* coors = (const int*)d_in[2];
  const float* W = (const float*)d_in[3];
  const float* gamma = (const float*)d_in[4];
  const float* beta = (const float*)d_in[5];
  float* out = (float*)d_out;

  const int K = in_sizes[1];
  const int P = in_sizes[0] / (K * 4);

  // ws layout (floats): ss[128] | ext[K*32 float4] | rec[K*2 float4]
  //                     | pA[10*NBA] | pB[44*NBB]   (~11 MB total)
  float* ss = (float*)d_ws;
  float4* ext = (float4*)(ss + 128);
  float4* rec = ext + (size_t)K * 32;
  float* pA = (float*)(rec + (size_t)K * 2);
  float* pB = pA + 10 * NBA;

  const int nwaves = NBA * 8;
  const int cnt = (K + nwaves - 1) / nwaves;

  pfn_main<<<NBA, 512, 0, stream>>>(feat, nvox, K, P, cnt, W, pA, ext, rec);
  pfn_cross<<<NBB, 256, 0, stream>>>(rec, coors, K, pB);
  pfn_finalize<<<1, 256, 0, stream>>>(pA, pB, W, gamma, beta,
                                      1.0f / (float)((long long)K * P), ss);
  pfn_apply<<<(K + 15) / 16, 512, 0, stream>>>(ext, rec, coors, W, ss, K, P,
                                               (f32x2*)out);
}

// Round 10
// 49.818 us; speedup vs baseline: 1.6128x; 1.0497x over previous
//
#include <hip/hip_runtime.h>

// PillarFeatureNet fused, 4 kernels, single feature read:
//  K1 pfn_main: wave-per-pillar-run; stages pillar to LDS; channel-quad
//     extrema: lane q=lane&15 owns channels 4q..4q+3 (sign(gamma)-folded
//     weights -> MAX only), point-group g=lane>>4 -> one ds_read_b128
//     serves 4 points x 64 channels. Per-lane raw second moments q2[10].
//     Per-pillar record rec[k]={sv[4]}{sa[3],nv} via pure-DPP reductions
//     (row butterfly + row_bcast15/31, total at lane 63; zero DS ops).
//  K1b pfn_cross: records -> Q1/S/U1/U2 cross-moment partials.
//  K2 pfn_finalize: reduce partials, assemble 54 augmented moments
//     (verified index maps), per-channel scale/shift.
//  K3 pfn_apply: per-pillar bias from rec, un-fold extremum by sign(scale)
//     (== sign(gamma)), masked clamp, BN affine + relu.
// features [K,P,4] f32, num_voxels [K] i32, coors [K,4] i32,
// W [9,64] f32, gamma/beta [64] f32 -> out [K,64] f32.

#define NBA 1252  // K1 blocks (divisible by 4 for K2 chunking)
#define NBB 64    // K1b blocks

// DPP butterfly within row16 (all-lane row sum), then row_bcast15 (rows 1,3)
// + row_bcast31 (rows 2,3): lane 63 holds the wave total. Pure VALU.
__device__ __forceinline__ float wred63(float v) {
  int t;
  t = __builtin_amdgcn_update_dpp(0, __float_as_int(v), 0xB1, 0xf, 0xf, true);
  v += __int_as_float(t);  // quad_perm(1,0,3,2) = xor1
  t = __builtin_amdgcn_update_dpp(0, __float_as_int(v), 0x4E, 0xf, 0xf, true);
  v += __int_as_float(t);  // quad_perm(2,3,0,1) = xor2
  t = __builtin_amdgcn_update_dpp(0, __float_as_int(v), 0x141, 0xf, 0xf, true);
  v += __int_as_float(t);  // row_half_mirror = xor7
  t = __builtin_amdgcn_update_dpp(0, __float_as_int(v), 0x140, 0xf, 0xf, true);
  v += __int_as_float(t);  // row_mirror = xor15 -> row-uniform sums
  t = __builtin_amdgcn_update_dpp(0, __float_as_int(v), 0x142, 0xa, 0xf, true);
  v += __int_as_float(t);  // row_bcast15 into rows 1,3
  t = __builtin_amdgcn_update_dpp(0, __float_as_int(v), 0x143, 0xc, 0xf, true);
  v += __int_as_float(t);  // row_bcast31 into rows 2,3 -> lane63 total
  return v;
}

// All-lane butterfly (DPP + 2 shfl) for K1b/K2 block reductions.
__device__ __forceinline__ float wred_add(float v) {
  int t;
  t = __builtin_amdgcn_update_dpp(0, __float_as_int(v), 0xB1, 0xf, 0xf, true);
  v += __int_as_float(t);
  t = __builtin_amdgcn_update_dpp(0, __float_as_int(v), 0x4E, 0xf, 0xf, true);
  v += __int_as_float(t);
  t = __builtin_amdgcn_update_dpp(0, __float_as_int(v), 0x141, 0xf, 0xf, true);
  v += __int_as_float(t);
  t = __builtin_amdgcn_update_dpp(0, __float_as_int(v), 0x140, 0xf, 0xf, true);
  v += __int_as_float(t);
  v += __shfl_xor(v, 16, 64);
  v += __shfl_xor(v, 32, 64);
  return v;
}

// ---------------- K1 ----------------
__global__ void __launch_bounds__(512) pfn_main(
    const float4* __restrict__ feat, const int* __restrict__ nvox, int K,
    int P, int cnt, const float* __restrict__ W,
    const float* __restrict__ gamma, float* __restrict__ pA,
    float4* __restrict__ ext, float4* __restrict__ rec) {
  __shared__ float4 pts[8][108];
  __shared__ float red[8][10];
  const int lane = threadIdx.x & 63;
  const int wid = threadIdx.x >> 6;
  const int q = lane & 15;  // channel quad (channels 4q..4q+3)
  const int g = lane >> 4;  // point group 0..3

  // sign(gamma)-folded weight quads (bias handled in K3 with raw weights)
  const float4* Wq = (const float4*)W;  // [9][16]
  const float4 g4 = ((const float4*)gamma)[q];
  float4 sg;
  sg.x = (g4.x >= 0.f) ? 1.f : -1.f;
  sg.y = (g4.y >= 0.f) ? 1.f : -1.f;
  sg.z = (g4.z >= 0.f) ? 1.f : -1.f;
  sg.w = (g4.w >= 0.f) ? 1.f : -1.f;
  const float4 a0 = Wq[0 * 16 + q], a1 = Wq[1 * 16 + q], a2 = Wq[2 * 16 + q];
  const float4 a3 = Wq[3 * 16 + q], a4 = Wq[4 * 16 + q], a5 = Wq[5 * 16 + q];
  const float4 a6 = Wq[6 * 16 + q], a7 = Wq[7 * 16 + q], a8 = Wq[8 * 16 + q];
  float4 wx, wy, wz, w3;
  wx.x = (a0.x + a4.x + a7.x) * sg.x; wx.y = (a0.y + a4.y + a7.y) * sg.y;
  wx.z = (a0.z + a4.z + a7.z) * sg.z; wx.w = (a0.w + a4.w + a7.w) * sg.w;
  wy.x = (a1.x + a5.x + a8.x) * sg.x; wy.y = (a1.y + a5.y + a8.y) * sg.y;
  wy.z = (a1.z + a5.z + a8.z) * sg.z; wy.w = (a1.w + a5.w + a8.w) * sg.w;
  wz.x = (a2.x + a6.x) * sg.x; wz.y = (a2.y + a6.y) * sg.y;
  wz.z = (a2.z + a6.z) * sg.z; wz.w = (a2.w + a6.w) * sg.w;
  w3.x = a3.x * sg.x; w3.y = a3.y * sg.y;
  w3.z = a3.z * sg.z; w3.w = a3.w * sg.w;

  float q2[10] = {0, 0, 0, 0, 0, 0, 0, 0, 0, 0};

  const int gw = blockIdx.x * 8 + wid;
  const int k0 = gw * cnt;
  const int kend = (k0 + cnt < K) ? k0 + cnt : K;
  const bool hih = lane < (P - 64);  // P in (64,128]

  for (int k = k0; k < kend; ++k) {
    const size_t base = (size_t)k * P;
    const float4 f0 = feat[base + lane];
    float4 f1;
    if (hih) f1 = feat[base + 64 + lane];
    const int nv = nvox[k];

    // ---- stage (single buffer; same-wave DS ordering keeps it safe) ----
    pts[wid][lane] = f0;
    if (hih) pts[wid][64 + lane] = f1;

    // ---- per-lane sums + raw second moments from registers ----
    float sax = f0.x, say = f0.y, saz = f0.z;
    float svx = 0, svy = 0, svz = 0, svw = 0;
    if (lane < nv) {
      svx = f0.x; svy = f0.y; svz = f0.z; svw = f0.w;
      q2[0] = fmaf(f0.x, f0.x, q2[0]); q2[1] = fmaf(f0.x, f0.y, q2[1]);
      q2[2] = fmaf(f0.x, f0.z, q2[2]); q2[3] = fmaf(f0.x, f0.w, q2[3]);
      q2[4] = fmaf(f0.y, f0.y, q2[4]); q2[5] = fmaf(f0.y, f0.z, q2[5]);
      q2[6] = fmaf(f0.y, f0.w, q2[6]); q2[7] = fmaf(f0.z, f0.z, q2[7]);
      q2[8] = fmaf(f0.z, f0.w, q2[8]); q2[9] = fmaf(f0.w, f0.w, q2[9]);
    }
    if (hih) {
      sax += f1.x; say += f1.y; saz += f1.z;
      if (64 + lane < nv) {
        svx += f1.x; svy += f1.y; svz += f1.z; svw += f1.w;
        q2[0] = fmaf(f1.x, f1.x, q2[0]); q2[1] = fmaf(f1.x, f1.y, q2[1]);
        q2[2] = fmaf(f1.x, f1.z, q2[2]); q2[3] = fmaf(f1.x, f1.w, q2[3]);
        q2[4] = fmaf(f1.y, f1.y, q2[4]); q2[5] = fmaf(f1.y, f1.z, q2[5]);
        q2[6] = fmaf(f1.y, f1.w, q2[6]); q2[7] = fmaf(f1.z, f1.z, q2[7]);
        q2[8] = fmaf(f1.z, f1.w, q2[8]); q2[9] = fmaf(f1.w, f1.w, q2[9]);
      }
    }

    // ---- 7 pure-DPP reductions (results at lane 63) ----
    const float rx = wred63(sax), ry = wred63(say), rz = wred63(saz);
    const float vx = wred63(svx), vy = wred63(svy);
    const float vz = wred63(svz), vw = wred63(svw);

    // ---- folded max over valid points: 1 ds_read = 4 points x 64 ch ----
    float4 m4 = {-3e38f, -3e38f, -3e38f, -3e38f};
    int p = 0;
    for (; p + 8 <= nv; p += 8) {
      const float4 fa = pts[wid][p + g];
      const float4 fb = pts[wid][p + 4 + g];
      m4.x = fmaxf(m4.x, fmaf(fa.x, wx.x, fmaf(fa.y, wy.x, fmaf(fa.z, wz.x, fa.w * w3.x))));
      m4.y = fmaxf(m4.y, fmaf(fa.x, wx.y, fmaf(fa.y, wy.y, fmaf(fa.z, wz.y, fa.w * w3.y))));
      m4.z = fmaxf(m4.z, fmaf(fa.x, wx.z, fmaf(fa.y, wy.z, fmaf(fa.z, wz.z, fa.w * w3.z))));
      m4.w = fmaxf(m4.w, fmaf(fa.x, wx.w, fmaf(fa.y, wy.w, fmaf(fa.z, wz.w, fa.w * w3.w))));
      m4.x = fmaxf(m4.x, fmaf(fb.x, wx.x, fmaf(fb.y, wy.x, fmaf(fb.z, wz.x, fb.w * w3.x))));
      m4.y = fmaxf(m4.y, fmaf(fb.x, wx.y, fmaf(fb.y, wy.y, fmaf(fb.z, wz.y, fb.w * w3.y))));
      m4.z = fmaxf(m4.z, fmaf(fb.x, wx.z, fmaf(fb.y, wy.z, fmaf(fb.z, wz.z, fb.w * w3.z))));
      m4.w = fmaxf(m4.w, fmaf(fb.x, wx.w, fmaf(fb.y, wy.w, fmaf(fb.z, wz.w, fb.w * w3.w))));
    }
    if (p < nv) {  // predicated tail octet (OOB reads masked, never used)
      const int i0 = p + g, i1 = p + 4 + g;
      const float4 fa = pts[wid][i0];
      const float4 fb = pts[wid][i1];
      if (i0 < nv) {
        m4.x = fmaxf(m4.x, fmaf(fa.x, wx.x, fmaf(fa.y, wy.x, fmaf(fa.z, wz.x, fa.w * w3.x))));
        m4.y = fmaxf(m4.y, fmaf(fa.x, wx.y, fmaf(fa.y, wy.y, fmaf(fa.z, wz.y, fa.w * w3.y))));
        m4.z = fmaxf(m4.z, fmaf(fa.x, wx.z, fmaf(fa.y, wy.z, fmaf(fa.z, wz.z, fa.w * w3.z))));
        m4.w = fmaxf(m4.w, fmaf(fa.x, wx.w, fmaf(fa.y, wy.w, fmaf(fa.z, wz.w, fa.w * w3.w))));
      }
      if (i1 < nv) {
        m4.x = fmaxf(m4.x, fmaf(fb.x, wx.x, fmaf(fb.y, wy.x, fmaf(fb.z, wz.x, fb.w * w3.x))));
        m4.y = fmaxf(m4.y, fmaf(fb.x, wx.y, fmaf(fb.y, wy.y, fmaf(fb.z, wz.y, fb.w * w3.y))));
        m4.z = fmaxf(m4.z, fmaf(fb.x, wx.z, fmaf(fb.y, wy.z, fmaf(fb.z, wz.z, fb.w * w3.z))));
        m4.w = fmaxf(m4.w, fmaf(fb.x, wx.w, fmaf(fb.y, wy.w, fmaf(fb.z, wz.w, fb.w * w3.w))));
      }
    }
    // cross-group max (lanes +-16, +-32)
    m4.x = fmaxf(m4.x, __shfl_xor(m4.x, 16, 64));
    m4.y = fmaxf(m4.y, __shfl_xor(m4.y, 16, 64));
    m4.z = fmaxf(m4.z, __shfl_xor(m4.z, 16, 64));
    m4.w = fmaxf(m4.w, __shfl_xor(m4.w, 16, 64));
    m4.x = fmaxf(m4.x, __shfl_xor(m4.x, 32, 64));
    m4.y = fmaxf(m4.y, __shfl_xor(m4.y, 32, 64));
    m4.z = fmaxf(m4.z, __shfl_xor(m4.z, 32, 64));
    m4.w = fmaxf(m4.w, __shfl_xor(m4.w, 32, 64));

    if (lane < 16) ext[(size_t)k * 16 + q] = m4;
    if (lane == 63) {
      float4 r0; r0.x = vx; r0.y = vy; r0.z = vz; r0.w = vw;
      float4 r1; r1.x = rx; r1.y = ry; r1.z = rz; r1.w = (float)nv;
      rec[2 * (size_t)k] = r0;
      rec[2 * (size_t)k + 1] = r1;
    }
  }

  // ---- block-level q2 partials (deterministic) ----
#pragma unroll
  for (int i = 0; i < 10; ++i) q2[i] = wred63(q2[i]);
  if (lane == 63) {
#pragma unroll
    for (int i = 0; i < 10; ++i) red[wid][i] = q2[i];
  }
  __syncthreads();
  const int t = threadIdx.x;
  if (t < 10) {
    float s = 0.f;
#pragma unroll
    for (int w = 0; w < 8; ++w) s += red[w][t];
    pA[t * NBA + blockIdx.x] = s;
  }
}

// ---------------- K1b: cross-moment aggregation from records ----------------
__global__ void __launch_bounds__(256) pfn_cross(
    const float4* __restrict__ rec, const int* __restrict__ coors, int K,
    float* __restrict__ pB) {
  __shared__ float red[4][44];
  const int lane = threadIdx.x & 63;
  const int wid = threadIdx.x >> 6;
  float q1[4] = {0, 0, 0, 0};
  float S[20];
  float u1[5] = {0, 0, 0, 0, 0};
  float u2[15];
#pragma unroll
  for (int i = 0; i < 20; ++i) S[i] = 0.f;
#pragma unroll
  for (int i = 0; i < 15; ++i) u2[i] = 0.f;

  for (int k = blockIdx.x * 256 + threadIdx.x; k < K; k += NBB * 256) {
    const float4 sv = rec[2 * (size_t)k];
    const float4 rb = rec[2 * (size_t)k + 1];
    const float nvf = rb.w, inv = 1.f / nvf;
    const float cx = (float)coors[k * 4 + 3] * 0.2f + 0.1f;
    const float cy = (float)coors[k * 4 + 2] * 0.2f - 39.9f;
    const float o[5] = {-rb.x * inv, -rb.y * inv, -rb.z * inv, -cx, -cy};
    const float s4[4] = {sv.x, sv.y, sv.z, sv.w};
#pragma unroll
    for (int a = 0; a < 4; ++a) q1[a] += s4[a];
#pragma unroll
    for (int a = 0; a < 4; ++a)
#pragma unroll
      for (int b = 0; b < 5; ++b)
        S[a * 5 + b] = fmaf(s4[a], o[b], S[a * 5 + b]);
    float no[5];
#pragma unroll
    for (int b = 0; b < 5; ++b) { no[b] = nvf * o[b]; u1[b] += no[b]; }
    int ui = 0;
#pragma unroll
    for (int b = 0; b < 5; ++b)
#pragma unroll
      for (int b2 = b; b2 < 5; ++b2) {
        u2[ui] = fmaf(no[b], o[b2], u2[ui]);
        ++ui;
      }
  }

  float a44[44];
#pragma unroll
  for (int i = 0; i < 4; ++i) a44[i] = q1[i];
#pragma unroll
  for (int i = 0; i < 20; ++i) a44[4 + i] = S[i];
#pragma unroll
  for (int i = 0; i < 5; ++i) a44[24 + i] = u1[i];
#pragma unroll
  for (int i = 0; i < 15; ++i) a44[29 + i] = u2[i];
#pragma unroll
  for (int i = 0; i < 44; ++i) a44[i] = wred_add(a44[i]);
  if (lane == 0) {
#pragma unroll
    for (int i = 0; i < 44; ++i) red[wid][i] = a44[i];
  }
  __syncthreads();
  const int t = threadIdx.x;
  if (t < 44)
    pB[t * NBB + blockIdx.x] =
        red[0][t] + red[1][t] + red[2][t] + red[3][t];
}

// ---------------- K2: reduce + assemble + scale/shift ----------------
__global__ void __launch_bounds__(256) pfn_finalize(
    const float* __restrict__ pA, const float* __restrict__ pB,
    const float* __restrict__ W, const float* __restrict__ gamma,
    const float* __restrict__ beta, float invN, float* __restrict__ ss) {
  __shared__ float msum[54];
  __shared__ float m54[54];
  const int t = threadIdx.x;
  const int r = t >> 2, j = t & 3;
  if (r < 54) {
    const float* row;
    int nb;
    if (r >= 4 && r < 14) { row = pA + (size_t)(r - 4) * NBA; nb = NBA; }
    else {
      const int br = (r < 4) ? r : (r - 10);
      row = pB + (size_t)br * NBB;
      nb = NBB;
    }
    const int chunk = nb >> 2;
    row += j * chunk;
    float a0 = 0, a1 = 0, a2 = 0, a3 = 0, a4 = 0, a5 = 0, a6 = 0, a7 = 0;
    int b = 0;
    for (; b + 8 <= chunk; b += 8) {
      a0 += row[b];     a1 += row[b + 1]; a2 += row[b + 2]; a3 += row[b + 3];
      a4 += row[b + 4]; a5 += row[b + 5]; a6 += row[b + 6]; a7 += row[b + 7];
    }
    for (; b < chunk; ++b) a0 += row[b];
    float s = ((a0 + a1) + (a2 + a3)) + ((a4 + a5) + (a6 + a7));
    s += __shfl_xor(s, 1, 64);
    s += __shfl_xor(s, 2, 64);
    if (j == 0) msum[r] = s;
  }
  __syncthreads();
  // msum layout: [0..3]=Q1 [4..13]=Q2 [14..33]=S [34..38]=U1 [39..53]=U2
  if (t < 54) {
    float v;
    if (t < 9) {
      const int g = (t < 4) ? t : (t < 7 ? t - 4 : t - 7);
      v = msum[g];
      if (t >= 4) v += msum[34 + (t - 4)];
    } else {
      int r2 = t - 9, c = 0;
      while (r2 >= 9 - c) { r2 -= 9 - c; ++c; }
      const int c2 = c + r2;
      const int a = (c < 4) ? c : (c < 7 ? c - 4 : c - 7);
      const int b2 = (c2 < 4) ? c2 : (c2 < 7 ? c2 - 4 : c2 - 7);
      const int lo = a < b2 ? a : b2, hi = a < b2 ? b2 : a;
      v = msum[4 + lo * (9 - lo) / 2 + (hi - lo)];  // 4x4 tri offsets 0/4/7/9
      if (c2 >= 4) v += msum[14 + a * 5 + (c2 - 4)];
      if (c >= 4) v += msum[14 + b2 * 5 + (c - 4)];
      if (c >= 4 && c2 >= 4) {
        const int ua = c - 4, ub = c2 - 4;  // ua <= ub
        v += msum[39 + ua * 5 - ua * (ua - 1) / 2 + (ub - ua)];
      }
    }
    m54[t] = v;
  }
  __syncthreads();
  if (t < 64) {
    float wc[9];
#pragma unroll
    for (int c = 0; c < 9; ++c) wc[c] = W[c * 64 + t];
    float mu = 0.f;
#pragma unroll
    for (int c = 0; c < 9; ++c) mu += m54[c] * invN * wc[c];
    float ex2 = 0.f;
    int idx = 9;
#pragma unroll
    for (int c = 0; c < 9; ++c)
#pragma unroll
      for (int c2 = c; c2 < 9; ++c2) {
        float v = m54[idx] * invN * wc[c] * wc[c2];
        ex2 += (c == c2) ? v : 2.f * v;
        ++idx;
      }
    const float var = ex2 - mu * mu;
    const float scale = gamma[t] * rsqrtf(var + 1e-3f);
    ss[t] = scale;
    ss[64 + t] = beta[t] - mu * scale;
  }
}

// ---------------- K3: bias + un-fold + BN + relu ----------------
__global__ void __launch_bounds__(256) pfn_apply(
    const float4* __restrict__ ext, const float4* __restrict__ rec,
    const int* __restrict__ coors, const float* __restrict__ W,
    const float* __restrict__ ss, int K, int P, float4* __restrict__ out) {
  const int t = blockIdx.x * 256 + threadIdx.x;
  if (t >= K * 16) return;
  const int k = t >> 4, j = t & 15;

  const float4* Wq = (const float4*)W;  // [9][16]
  const float4 v4 = Wq[4 * 16 + j], v5 = Wq[5 * 16 + j];
  const float4 v6 = Wq[6 * 16 + j], v7 = Wq[7 * 16 + j];
  const float4 v8 = Wq[8 * 16 + j];

  const float4 e = ext[t];
  const float4 rb = rec[2 * (size_t)k + 1];
  const float nvf = rb.w, inv = 1.f / nvf;
  const float cx = (float)coors[k * 4 + 3] * 0.2f + 0.1f;
  const float cy = (float)coors[k * 4 + 2] * 0.2f - 39.9f;
  const float o0 = -rb.x * inv, o1 = -rb.y * inv, o2 = -rb.z * inv;
  float4 bias;
  bias.x = v4.x * o0 + v5.x * o1 + v6.x * o2 - v7.x * cx - v8.x * cy;
  bias.y = v4.y * o0 + v5.y * o1 + v6.y * o2 - v7.y * cx - v8.y * cy;
  bias.z = v4.z * o0 + v5.z * o1 + v6.z * o2 - v7.z * cx - v8.z * cy;
  bias.w = v4.w * o0 + v5.w * o1 + v6.w * o2 - v7.w * cx - v8.w * cy;

  const float4 sc = ((const float4*)ss)[j];
  const float4 sh = ((const float4*)(ss + 64))[16 - 16 + j];  // ss+64 quads
  const bool masked = nvf < (float)P;

  float4 o;
  {
    const float sgn = (sc.x >= 0.f) ? 1.f : -1.f;
    float ev = sgn * e.x + bias.x;
    if (masked) ev = (sc.x >= 0.f) ? fmaxf(ev, 0.f) : fminf(ev, 0.f);
    o.x = fmaxf(fmaf(sc.x, ev, sh.x), 0.f);
  }
  {
    const float sgn = (sc.y >= 0.f) ? 1.f : -1.f;
    float ev = sgn * e.y + bias.y;
    if (masked) ev = (sc.y >= 0.f) ? fmaxf(ev, 0.f) : fminf(ev, 0.f);
    o.y = fmaxf(fmaf(sc.y, ev, sh.y), 0.f);
  }
  {
    const float sgn = (sc.z >= 0.f) ? 1.f : -1.f;
    float ev = sgn * e.z + bias.z;
    if (masked) ev = (sc.z >= 0.f) ? fmaxf(ev, 0.f) : fminf(ev, 0.f);
    o.z = fmaxf(fmaf(sc.z, ev, sh.z), 0.f);
  }
  {
    const float sgn = (sc.w >= 0.f) ? 1.f : -1.f;
    float ev = sgn * e.w + bias.w;
    if (masked) ev = (sc.w >= 0.f) ? fmaxf(ev, 0.f) : fminf(ev, 0.f);
    o.w = fmaxf(fmaf(sc.w, ev, sh.w), 0.f);
  }
  out[t] = o;
}

extern "C" void kernel_launch(void* const* d_in, const int* in_sizes, int n_in,
                              void* d_out, int out_size, void* d_ws,
                              size_t ws_size, hipStream_t stream) {
  const float4* feat = (const float4*)d_in[0];
  const int* nvox = (const int*)d_in[1];
  const int* coors = (const int*)d_in[2];
  const float* W = (const float*)d_in[3];
  const float* gamma = (const float*)d_in[4];
  const float* beta = (const float*)d_in[5];

  const int K = in_sizes[1];
  const int P = in_sizes[0] / (K * 4);

  // ws layout (floats): ss[128] | ext[K*16 float4] | rec[K*2 float4]
  //                     | pA[10*NBA] | pB[44*NBB]   (~6 MB total)
  float* ss = (float*)d_ws;
  float4* ext = (float4*)(ss + 128);
  float4* rec = ext + (size_t)K * 16;
  float* pA = (float*)(rec + (size_t)K * 2);
  float* pB = pA + 10 * NBA;

  const int nwaves = NBA * 8;
  const int cnt = (K + nwaves - 1) / nwaves;

  pfn_main<<<NBA, 512, 0, stream>>>(feat, nvox, K, P, cnt, W, gamma, pA, ext,
                                    rec);
  pfn_cross<<<NBB, 256, 0, stream>>>(rec, coors, K, pB);
  pfn_finalize<<<1, 256, 0, stream>>>(pA, pB, W, gamma, beta,
                                      1.0f / (float)((long long)K * P), ss);
  pfn_apply<<<(K * 16 + 255) / 256, 256, 0, stream>>>(ext, rec, coors, W, ss,
                                                      K, P, (float4*)d_out);
}